// Round 6
// baseline (382.925 us; speedup 1.0000x reference)
//
#include <hip/hip_runtime.h>
#include <hip/hip_bf16.h>
#include <hip/hip_fp16.h>

typedef __attribute__((ext_vector_type(8))) short short8;   // 8 bf16 in 4 VGPRs
typedef __attribute__((ext_vector_type(4))) float floatx4;  // MFMA accumulator

#define DFEAT 128
#define BCAP 5120    // degree safety clamp (also fallback bucket cap)
#define WSTR 136     // LDS row stride (ushorts): 16B-aligned, <=2-way bank aliasing
#define MAXNBK 400   // bucket count cap (ceil(100000/256)=391)

__device__ __forceinline__ int clampi(int v, int lo, int hi) {
    return v < lo ? lo : (v > hi ? hi : v);
}
__device__ __forceinline__ ushort f2bf(float f) {  // RNE f32->bf16 bits
    unsigned u = __float_as_uint(f);
    unsigned r = (u + 0x7FFFu + ((u >> 16) & 1u)) >> 16;
    return (ushort)r;
}
__device__ __forceinline__ float bf2f(ushort u) {
    return __uint_as_float(((unsigned)u) << 16);
}
__device__ __forceinline__ float h16tof(ushort hb) {
    __half_raw hr; hr.x = hb;
    return __half2float((__half)hr);
}
__device__ __forceinline__ unsigned f2bf8_sw(float f) {   // f32 -> e5m2 byte
    __half h = __float2half(f);
    __half_raw hr = (__half_raw)h;
    unsigned u = (unsigned)hr.x;
    return (u + 0x7Fu + ((u >> 8) & 1u)) >> 8;
}
__device__ __forceinline__ unsigned packbf8x4(float4 v) {
#if __has_builtin(__builtin_amdgcn_cvt_pk_bf8_f32)
    int lo = __builtin_amdgcn_cvt_pk_bf8_f32(v.x, v.y, 0, false);
    int full = __builtin_amdgcn_cvt_pk_bf8_f32(v.z, v.w, lo, true);
    return (unsigned)full;
#else
    return f2bf8_sw(v.x) | (f2bf8_sw(v.y) << 8) | (f2bf8_sw(v.z) << 16) | (f2bf8_sw(v.w) << 24);
#endif
}
__device__ __forceinline__ float2 bf8x2tof(int w) {       // 2 e5m2 (low 16b) -> 2 f32
#if __has_builtin(__builtin_amdgcn_cvt_pk_f32_bf8)
    typedef __attribute__((ext_vector_type(2))) float f2v;
    f2v r = __builtin_amdgcn_cvt_pk_f32_bf8(w, false);
    float2 o; o.x = r[0]; o.y = r[1];
    return o;
#else
    float2 o;
    o.x = h16tof((ushort)((w & 0xFF) << 8));
    o.y = h16tof((ushort)(w & 0xFF00));
    return o;
#endif
}

__device__ __forceinline__ int ldS(const int* adj, int f, int E, int e) {
    return f ? adj[2 * (size_t)e] : adj[e];
}
__device__ __forceinline__ int ldR(const int* adj, int f, int E, int e) {
    return f ? adj[2 * ((size_t)E + e)] : adj[(size_t)E + e];
}

// ================= STAGED PATH: global counting sort =================

// k_hist: SG staging blocks (x->fp8, Wb pack) + PB hist blocks (adj pass 1,
// global atomics into deg_s/deg_r -- 100K L2-resident counters each).
__global__ __launch_bounds__(512) void k_hist(const float* __restrict__ x,
                                              unsigned* __restrict__ xs, int n32,
                                              const float* __restrict__ W, unsigned* __restrict__ Wb,
                                              const int* __restrict__ adj, int* __restrict__ flag_g,
                                              int* __restrict__ deg_s, int* __restrict__ deg_r,
                                              int E, int N, int SG) {
    int t = threadIdx.x;
    int b = blockIdx.x;
    if (b < SG) {
        if (b == 0) {                                 // W f32 -> packed bf16x2
            for (int i = t; i < 8192; i += 512) {
                float2 v = ((const float2*)W)[i];
                Wb[i] = (unsigned)f2bf(v.x) | ((unsigned)f2bf(v.y) << 16);
            }
        }
        int stride = SG * 512;
        for (int i = b * 512 + t; i < n32; i += stride)
            xs[i] = packbf8x4(((const float4*)x)[i]);
        return;
    }
    __shared__ int fsh;
    int pb = b - SG;
    int PB = gridDim.x - SG;
    if (t < 64) {                                     // self-detect adj dtype
        int nz = 0;
        for (int i = t; i < 256; i += 64) nz |= adj[2 * i + 1];
        #pragma unroll
        for (int off = 32; off > 0; off >>= 1) nz |= __shfl_down(nz, off);
        if (t == 0) { fsh = (nz == 0) ? 1 : 0; if (pb == 0) flag_g[0] = fsh; }
    }
    __syncthreads();
    int f = fsh;
    int chunk = (E + PB - 1) / PB;
    int e0 = pb * chunk;
    int e1 = min(E, e0 + chunk);
    for (int e = e0 + t; e < e1; e += 512) {
        int s = clampi(ldS(adj, f, E, e), 0, N - 1);
        int r = clampi(ldR(adj, f, E, e), 0, N - 1);
        atomicAdd(&deg_s[s], 1);
        atomicAdd(&deg_r[r], 1);
    }
}

// k_scan1: per-256-node block: exclusive scan of deg_r -> svl (bucket-local) +
// cursor init; psum[b] = bucket total; inv_s = rsqrt(max(deg_s,1)).
__global__ __launch_bounds__(256) void k_scan1(const int* __restrict__ deg_r,
                                               const int* __restrict__ deg_s,
                                               int* __restrict__ svl, int* __restrict__ cur,
                                               float* __restrict__ inv_s,
                                               int* __restrict__ psum, int N) {
    __shared__ int sh[256];
    int b = blockIdx.x, t = threadIdx.x;
    int node = (b << 8) + t;
    int v = (node < N) ? deg_r[node] : 0;
    sh[t] = v;
    __syncthreads();
    for (int o = 1; o < 256; o <<= 1) {
        int u = (t >= o) ? sh[t - o] : 0;
        __syncthreads();
        sh[t] += u;
        __syncthreads();
    }
    int excl = sh[t] - v;
    if (node < N) {
        svl[node] = excl;
        cur[node] = 0;
        inv_s[node] = rsqrtf(fmaxf((float)deg_s[node], 1.0f));
    }
    if (t == 255) psum[b] = sh[255];
}

// k_scan2: single block: exclusive scan of psum[NB] (NB<=512).
__global__ __launch_bounds__(512) void k_scan2(int* __restrict__ psum, int NB) {
    __shared__ int sh[512];
    int t = threadIdx.x;
    int v = (t < NB) ? psum[t] : 0;
    sh[t] = v;
    __syncthreads();
    for (int o = 1; o < 512; o <<= 1) {
        int u = (t >= o) ? sh[t - o] : 0;
        __syncthreads();
        sh[t] += u;
        __syncthreads();
    }
    if (t < NB) psum[t] = sh[t] - v;
}

// k_scatter: adj pass 2: slot = psum[r>>8] + svl[r] + atomicAdd(&cur[r],1);
// rbuf[slot] = s | e5m2(inv_s[s])<<24  (exact format k_back consumes).
__global__ __launch_bounds__(512) void k_scatter(const int* __restrict__ adj,
                                                 const int* __restrict__ flag,
                                                 const float* __restrict__ inv_s,
                                                 const int* __restrict__ psum,
                                                 const int* __restrict__ svl,
                                                 int* __restrict__ cur,
                                                 unsigned* __restrict__ rbuf, int E, int N) {
    int t = threadIdx.x;
    int pb = blockIdx.x;
    int PB = gridDim.x;
    int f = flag[0];
    int chunk = (E + PB - 1) / PB;
    int e0 = pb * chunk;
    int e1 = min(E, e0 + chunk);
    for (int e = e0 + t; e < e1; e += 512) {
        int s = clampi(ldS(adj, f, E, e), 0, N - 1);
        int r = clampi(ldR(adj, f, E, e), 0, N - 1);
        unsigned iv8 = f2bf8_sw(inv_s[s]);
        int pos = psum[r >> 8] + svl[r] + atomicAdd(&cur[r], 1);
        if (pos >= 0 && pos < E) rbuf[pos] = (unsigned)s | (iv8 << 24);
    }
}

// k_back_g: byte-identical hot loop to the proven 83.5us k_back; only the
// base computation (svl+psum instead of startv) differs. adjcopy role fused.
__global__ __launch_bounds__(512) void k_back_g(const ushort* __restrict__ xs,
                                                const float* __restrict__ bias,
                                                const unsigned* __restrict__ Wb,
                                                const int* __restrict__ svl,
                                                const int* __restrict__ psum,
                                                const int* __restrict__ deg_r,
                                                const unsigned* __restrict__ esrc,
                                                float* __restrict__ out0, int N, int RB, int ntiles,
                                                const int* __restrict__ adj, const int* __restrict__ flag,
                                                float* __restrict__ out1, int n1) {
    __shared__ ushort Wt[128 * WSTR];   // 34816 B
    __shared__ ushort At[32 * WSTR];    // 8704 B
    __shared__ float csrow[32], invrow[32];
    int tid = threadIdx.x;

    if ((int)blockIdx.x >= ntiles) {    // adjcopy role
        int f = flag[0];
        int nb = gridDim.x - ntiles;
        for (int i = ((int)blockIdx.x - ntiles) * 512 + tid; i < n1; i += nb * 512) {
            int v = f ? adj[2 * (size_t)i] : adj[i];
            out1[i] = bf2f(f2bf((float)v));
        }
        return;
    }

    int m0 = blockIdx.x * 32;
    for (int i = tid; i < 8192; i += 512) {          // stage W (pre-packed bf16)
        unsigned v = Wb[i];
        int row = i >> 6, col = (2 * i) & 127;
        *(unsigned*)(&Wt[row * WSTR + col]) = v;
    }

    int w = tid >> 6, d = tid & 63;
    #pragma unroll 1
    for (int k = 0; k < 4; ++k) {                    // aggregate 4 nodes per wave
        int nl = w * 4 + k;
        int node = m0 + nl;
        int cnt = 0, base = 0;
        if (node < N) {
            cnt = clampi(deg_r[node], 0, BCAP);
            base = clampi(svl[node] + psum[node >> 8], 0, RB - cnt);
        }
        cnt = __builtin_amdgcn_readfirstlane(cnt);
        base = __builtin_amdgcn_readfirstlane(base);
        const unsigned* ep = esrc + base;
        float a0 = 0.f, a1 = 0.f, cs = 0.f;
        int j = 0;
        for (; j + 7 < cnt; j += 8) {
            unsigned q0 = ep[j],     q1 = ep[j + 1], q2 = ep[j + 2], q3 = ep[j + 3];
            unsigned q4 = ep[j + 4], q5 = ep[j + 5], q6 = ep[j + 6], q7 = ep[j + 7];
            int r0 = (int)xs[((q0 & 0x1FFFFu) << 6) + d];
            int r1 = (int)xs[((q1 & 0x1FFFFu) << 6) + d];
            int r2 = (int)xs[((q2 & 0x1FFFFu) << 6) + d];
            int r3 = (int)xs[((q3 & 0x1FFFFu) << 6) + d];
            int r4 = (int)xs[((q4 & 0x1FFFFu) << 6) + d];
            int r5 = (int)xs[((q5 & 0x1FFFFu) << 6) + d];
            int r6 = (int)xs[((q6 & 0x1FFFFu) << 6) + d];
            int r7 = (int)xs[((q7 & 0x1FFFFu) << 6) + d];
            float v0 = h16tof((ushort)((q0 >> 16) & 0xFF00u));
            float v1 = h16tof((ushort)((q1 >> 16) & 0xFF00u));
            float v2 = h16tof((ushort)((q2 >> 16) & 0xFF00u));
            float v3 = h16tof((ushort)((q3 >> 16) & 0xFF00u));
            float v4 = h16tof((ushort)((q4 >> 16) & 0xFF00u));
            float v5 = h16tof((ushort)((q5 >> 16) & 0xFF00u));
            float v6 = h16tof((ushort)((q6 >> 16) & 0xFF00u));
            float v7 = h16tof((ushort)((q7 >> 16) & 0xFF00u));
            float2 f0 = bf8x2tof(r0), f1 = bf8x2tof(r1), f2 = bf8x2tof(r2), f3 = bf8x2tof(r3);
            float2 f4 = bf8x2tof(r4), f5 = bf8x2tof(r5), f6 = bf8x2tof(r6), f7 = bf8x2tof(r7);
            a0 += v0 * f0.x; a1 += v0 * f0.y;
            a0 += v1 * f1.x; a1 += v1 * f1.y;
            a0 += v2 * f2.x; a1 += v2 * f2.y;
            a0 += v3 * f3.x; a1 += v3 * f3.y;
            a0 += v4 * f4.x; a1 += v4 * f4.y;
            a0 += v5 * f5.x; a1 += v5 * f5.y;
            a0 += v6 * f6.x; a1 += v6 * f6.y;
            a0 += v7 * f7.x; a1 += v7 * f7.y;
            cs += ((v0 + v1) + (v2 + v3)) + ((v4 + v5) + (v6 + v7));
        }
        for (; j < cnt; ++j) {
            unsigned q0 = ep[j];
            float v0 = h16tof((ushort)((q0 >> 16) & 0xFF00u));
            float2 f0 = bf8x2tof((int)xs[((q0 & 0x1FFFFu) << 6) + d]);
            a0 += v0 * f0.x; a1 += v0 * f0.y;
            cs += v0;
        }
        ushort2 p; p.x = f2bf(a0); p.y = f2bf(a1);
        *(ushort2*)(&At[nl * WSTR + 2 * d]) = p;
        if (d == 0) {
            csrow[nl] = cs;
            invrow[nl] = rsqrtf(fmaxf((float)cnt, 1.0f));
        }
    }
    __syncthreads();

    int quad = d >> 4, r16 = d & 15;
    int rt = w & 1;
    short8 a[4];
    #pragma unroll
    for (int g = 0; g < 4; ++g)
        a[g] = *(const short8*)(&At[(rt * 16 + r16) * WSTR + g * 32 + quad * 8]);

    #pragma unroll
    for (int half = 0; half < 2; ++half) {
        int ct = (w >> 1) + half * 4;
        floatx4 acc = {0.f, 0.f, 0.f, 0.f};
        #pragma unroll
        for (int g = 0; g < 4; ++g) {
            short8 bb = *(const short8*)(&Wt[(ct * 16 + r16) * WSTR + g * 32 + quad * 8]);
            acc = __builtin_amdgcn_mfma_f32_16x16x32_bf16(a[g], bb, acc, 0, 0, 0);
        }
        int dcol = ct * 16 + r16;
        float bc = bias[dcol];
        #pragma unroll
        for (int g = 0; g < 4; ++g) {
            int ml = rt * 16 + quad * 4 + g;
            int grow = m0 + ml;
            if (grow < N) {
                float v = (acc[g] + csrow[ml] * bc) * invrow[ml];
                float z = v / (1.0f + __expf(-v));            // silu
                if (!(z > -50.0f && z < 50.0f)) z = 0.0f;     // insurance, no-op when correct
                out0[(size_t)grow * DFEAT + dcol] = z;
            }
        }
    }
}

// ================= fallback path kernels (unchanged, used when ws too small) =================
__global__ __launch_bounds__(512) void k_front(const float* __restrict__ x,
                                               unsigned* __restrict__ xs, int n32, int staged,
                                               const float* __restrict__ W, unsigned* __restrict__ Wb,
                                               const int* __restrict__ adj, int* __restrict__ flag_g,
                                               int* __restrict__ scur, int* __restrict__ rcur,
                                               unsigned char* __restrict__ sbuf, unsigned* __restrict__ rbuf,
                                               int E, int N, int NBK, int SG) {
    int t = threadIdx.x;
    int b = blockIdx.x;
    if (b < SG) {
        if (b == 0) {
            for (int i = t; i < 8192; i += 512) {
                float2 v = ((const float2*)W)[i];
                Wb[i] = (unsigned)f2bf(v.x) | ((unsigned)f2bf(v.y) << 16);
            }
        }
        if (staged) {
            int stride = SG * 512;
            for (int i = b * 512 + t; i < n32; i += stride)
                xs[i] = packbf8x4(((const float4*)x)[i]);
        }
        return;
    }
    __shared__ int hs[8 * MAXNBK], hr[8 * MAXNBK];
    __shared__ int bs[MAXNBK], br[MAXNBK];
    __shared__ int fsh;
    int pb = b - SG;
    int PB = gridDim.x - SG;
    int wv = t >> 6, ln = t & 63;
    if (t < 64) {
        int nz = 0;
        for (int i = t; i < 256; i += 64) nz |= adj[2 * i + 1];
        #pragma unroll
        for (int off = 32; off > 0; off >>= 1) nz |= __shfl_down(nz, off);
        if (t == 0) { fsh = (nz == 0) ? 1 : 0; if (pb == 0) flag_g[0] = fsh; }
    }
    for (int i = t; i < 8 * MAXNBK; i += 512) { hs[i] = 0; hr[i] = 0; }
    __syncthreads();
    int f = fsh;
    int chunk = (E + PB - 1) / PB;
    int e0 = pb * chunk;
    int e1 = min(E, e0 + chunk);
    int span = e1 - e0;
    int wper = (span + 7) >> 3;
    int a0 = e0 + wv * wper;
    int a1 = min(e1, a0 + wper);
    int* mys = &hs[wv * MAXNBK];
    int* myr = &hr[wv * MAXNBK];
    for (int e = a0 + ln; e < a1; e += 64) {
        int s = clampi(ldS(adj, f, E, e), 0, N - 1);
        int r = clampi(ldR(adj, f, E, e), 0, N - 1);
        atomicAdd(&mys[s >> 8], 1);
        atomicAdd(&myr[r >> 8], 1);
    }
    __syncthreads();
    for (int i = t; i < NBK; i += 512) {
        int aS = 0, aR = 0;
        #pragma unroll
        for (int w = 0; w < 8; ++w) {
            int vS = hs[w * MAXNBK + i]; hs[w * MAXNBK + i] = aS; aS += vS;
            int vR = hr[w * MAXNBK + i]; hr[w * MAXNBK + i] = aR; aR += vR;
        }
        bs[i] = aS ? atomicAdd(&scur[i], aS) : 0;
        br[i] = aR ? atomicAdd(&rcur[i], aR) : 0;
    }
    __syncthreads();
    for (int e = a0 + ln; e < a1; e += 64) {
        int s = clampi(ldS(adj, f, E, e), 0, N - 1);
        int r = clampi(ldR(adj, f, E, e), 0, N - 1);
        int ps = bs[s >> 8] + atomicAdd(&mys[s >> 8], 1);
        if (ps < BCAP) sbuf[(size_t)(s >> 8) * BCAP + ps] = (unsigned char)(s & 255);
        int pr = br[r >> 8] + atomicAdd(&myr[r >> 8], 1);
        if (pr < BCAP) rbuf[(size_t)(r >> 8) * BCAP + pr] = ((unsigned)(r & 255) << 17) | (unsigned)s;
    }
}

__global__ __launch_bounds__(256) void k_invs(const unsigned char* __restrict__ sbuf,
                                              const int* __restrict__ scur,
                                              float* __restrict__ inv_s, int N) {
    __shared__ int h[256];
    int b = blockIdx.x, t = threadIdx.x;
    int sc = min(scur[b], BCAP);
    const unsigned char* sb = sbuf + (size_t)b * BCAP;
    h[t] = 0;
    __syncthreads();
    for (int i = t; i < sc; i += 256) atomicAdd(&h[sb[i]], 1);
    __syncthreads();
    int node = (b << 8) + t;
    if (node < N) inv_s[node] = rsqrtf(fmaxf((float)h[t], 1.0f));
}

__global__ __launch_bounds__(256) void k_sort(unsigned* __restrict__ rbuf,
                                              const int* __restrict__ rcur,
                                              const float* __restrict__ inv_s,
                                              int* __restrict__ deg_r, int* __restrict__ startv,
                                              int N) {
    __shared__ __align__(16) unsigned pk[BCAP];
    __shared__ int h[256], off[256];
    int b = blockIdx.x, t = threadIdx.x;
    int node = (b << 8) + t;
    int cnt = min(rcur[b], BCAP);
    unsigned* rb = rbuf + (size_t)b * BCAP;
    int cnt4 = cnt >> 2;
    const uint4* rb4 = (const uint4*)rb;
    for (int i = t; i < cnt4; i += 256) ((uint4*)pk)[i] = rb4[i];
    for (int i = (cnt4 << 2) + t; i < cnt; i += 256) pk[i] = rb[i];
    h[t] = 0;
    __syncthreads();
    for (int i = t; i < cnt; i += 256) atomicAdd(&h[pk[i] >> 17], 1);
    __syncthreads();
    int hv = h[t];
    off[t] = hv;
    __syncthreads();
    for (int o = 1; o < 256; o <<= 1) {
        int v = (t >= o) ? off[t - o] : 0;
        __syncthreads();
        off[t] += v;
        __syncthreads();
    }
    int excl = off[t] - hv;
    if (node < N) { deg_r[node] = hv; startv[node] = b * BCAP + excl; }
    __syncthreads();
    h[t] = excl;
    __syncthreads();
    for (int i = t; i < cnt; i += 256) {
        unsigned v = pk[i];
        int s = (int)(v & 0x1FFFFu);
        unsigned iv8 = f2bf8_sw(inv_s[clampi(s, 0, N - 1)]);
        int pos = atomicAdd(&h[v >> 17], 1);
        if (pos >= 0 && pos < cnt) rb[pos] = (v & 0x1FFFFu) | (iv8 << 24);
    }
}

__global__ __launch_bounds__(256) void k_aggregate_fb(const float* __restrict__ x,
                                                      const int* __restrict__ startv,
                                                      const int* __restrict__ deg_r,
                                                      const unsigned* __restrict__ esrc,
                                                      float* __restrict__ xa,
                                                      float* __restrict__ cvec, int N, int RB) {
    int node = blockIdx.x * 4 + (threadIdx.x >> 6);
    int d = threadIdx.x & 63;
    if (node >= N) return;
    int cnt = clampi(deg_r[node], 0, BCAP);
    int base = clampi(startv[node], 0, RB - cnt);
    cnt = __builtin_amdgcn_readfirstlane(cnt);
    base = __builtin_amdgcn_readfirstlane(base);
    const unsigned* ep = esrc + base;
    float a0 = 0.f, a1 = 0.f, cs = 0.f;
    for (int j = 0; j < cnt; ++j) {
        unsigned w0 = ep[j];
        int s0 = (int)(w0 & 0x1FFFFu);
        float v0 = h16tof((ushort)((w0 >> 16) & 0xFF00u));
        float2 f0 = ((const float2*)x)[(size_t)s0 * 64 + d];
        a0 += v0 * f0.x; a1 += v0 * f0.y;
        cs += v0;
    }
    float2 o; o.x = a0; o.y = a1;
    ((float2*)xa)[(size_t)node * 64 + d] = o;
    if (d == 0) cvec[node] = cs;
}

__global__ __launch_bounds__(256) void k_matmul_fb(float* __restrict__ xa,
                                                   const unsigned* __restrict__ Wb,
                                                   const float* __restrict__ bias,
                                                   const float* __restrict__ c,
                                                   const int* __restrict__ deg_r, int M) {
    __shared__ ushort Wt[128 * WSTR];
    __shared__ ushort At[64 * WSTR];
    int tid = threadIdx.x;
    int m0 = blockIdx.x * 64;
    for (int i = tid; i < 8192; i += 256) {
        unsigned v = Wb[i];
        int row = i >> 6, col = (2 * i) & 127;
        *(unsigned*)(&Wt[row * WSTR + col]) = v;
    }
    for (int i = tid; i < 4096; i += 256) {
        int row = i >> 6, col = (2 * i) & 127;
        int grow = m0 + row;
        float2 v;
        if (grow < M) v = ((const float2*)xa)[(size_t)grow * 64 + (col >> 1)];
        else { v.x = 0.f; v.y = 0.f; }
        ushort2 p; p.x = f2bf(v.x); p.y = f2bf(v.y);
        *(ushort2*)(&At[row * WSTR + col]) = p;
    }
    __syncthreads();
    int wid = tid >> 6, lane = tid & 63;
    int quad = lane >> 4, r16 = lane & 15;
    short8 a[4];
    #pragma unroll
    for (int g = 0; g < 4; ++g)
        a[g] = *(const short8*)(&At[(wid * 16 + r16) * WSTR + g * 32 + quad * 8]);
    int rbl = wid * 16 + quad * 4;
    float cg[4], invr[4];
    #pragma unroll
    for (int g = 0; g < 4; ++g) {
        int row = min(m0 + rbl + g, M - 1);
        cg[g] = c[row];
        invr[g] = rsqrtf(fmaxf((float)deg_r[row], 1.0f));
    }
    #pragma unroll
    for (int nt = 0; nt < 8; ++nt) {
        floatx4 acc = {0.f, 0.f, 0.f, 0.f};
        #pragma unroll
        for (int g = 0; g < 4; ++g) {
            short8 bb = *(const short8*)(&Wt[(nt * 16 + r16) * WSTR + g * 32 + quad * 8]);
            acc = __builtin_amdgcn_mfma_f32_16x16x32_bf16(a[g], bb, acc, 0, 0, 0);
        }
        int dcol = nt * 16 + r16;
        float bc = bias[dcol];
        #pragma unroll
        for (int g = 0; g < 4; ++g) {
            int grow = m0 + rbl + g;
            if (grow < M) {
                float v = (acc[g] + cg[g] * bc) * invr[g];
                float z = v / (1.0f + __expf(-v));
                if (!(z > -50.0f && z < 50.0f)) z = 0.0f;
                xa[(size_t)grow * DFEAT + dcol] = z;
            }
        }
    }
}

__global__ void k_adjcopy(const int* __restrict__ adj, const int* __restrict__ flag,
                          float* __restrict__ out, int n) {
    int i = blockIdx.x * 256 + threadIdx.x;
    if (i >= n) return;
    int f = flag[0];
    int v = f ? adj[2 * (size_t)i] : adj[i];
    out[i] = bf2f(f2bf((float)v));
}

extern "C" void kernel_launch(void* const* d_in, const int* in_sizes, int n_in,
                              void* d_out, int out_size, void* d_ws, size_t ws_size,
                              hipStream_t stream) {
    const float* x    = (const float*)d_in[0];   // f32 [N,128]
    const int*   adj  = (const int*)d_in[1];     // int32 or int64 [2,E]
    const float* W    = (const float*)d_in[2];   // f32 [128,128]
    const float* bias = (const float*)d_in[3];   // f32 [128]

    const int N = in_sizes[0] / DFEAT;           // 100000
    const int E = (out_size - N * DFEAT) / 2;    // 1600000
    const int NBK = (N + 255) >> 8;              // 391 buckets of 256 nodes
    const int N4 = ((N + 255) / 256) * 256;

    float* out  = (float*)d_out;
    float* out0 = out;
    float* out1 = out + (size_t)N * DFEAT;

    size_t xsB   = (size_t)N * DFEAT;            // 12.8 MB e5m2 rows
    size_t rbB   = (size_t)E * 4;                // 6.4 MB exact edge array
    size_t metaB = (size_t)N4 * 20 + 8192 + 32768;
    size_t need  = xsB + rbB + metaB + 4096;
    int staged = (ws_size >= need) ? 1 : 0;

    if (staged) {
        ushort* xs = (ushort*)d_ws;
        unsigned* rbuf = (unsigned*)((char*)d_ws + xsB);
        char* csr = (char*)d_ws + xsB + rbB;
        int*   deg_s = (int*)csr;
        int*   deg_r = deg_s + N4;
        int*   svl   = deg_r + N4;
        int*   cur   = svl + N4;
        float* inv_s = (float*)(cur + N4);
        int*   psum  = (int*)(inv_s + N4);       // 512 ints
        int*   flag  = psum + 512;
        unsigned* Wb = (unsigned*)(flag + 512);

        hipMemsetAsync(deg_s, 0, (size_t)N4 * 8, stream);   // deg_s + deg_r

        int SG = 512, PB = 256;
        k_hist<<<SG + PB, 512, 0, stream>>>(x, (unsigned*)xs, N * 32, W, Wb, adj, flag,
                                            deg_s, deg_r, E, N, SG);
        k_scan1<<<NBK, 256, 0, stream>>>(deg_r, deg_s, svl, cur, inv_s, psum, N);
        k_scan2<<<1, 512, 0, stream>>>(psum, NBK);
        k_scatter<<<256, 512, 0, stream>>>(adj, flag, inv_s, psum, svl, cur, rbuf, E, N);
        int ntiles = (N + 31) / 32;
        k_back_g<<<ntiles + 256, 512, 0, stream>>>(xs, bias, Wb, svl, psum, deg_r, rbuf,
                                                   out0, N, E, ntiles, adj, flag, out1, 2 * E);
        return;
    }

    // ---------- fallback (ws too small): R5 pipeline in output regions ----------
    const int RB = NBK * BCAP;
    size_t sbB = ((size_t)NBK * BCAP + 255) & ~(size_t)255;
    size_t rbBf = (size_t)RB * 4;
    size_t metaBf = (size_t)N4 * 16 + 8192;
    unsigned char* sbuf = (unsigned char*)d_out;
    unsigned* rbuf = (unsigned*)out1;
    char* csr = (char*)out1 + rbBf;
    (void)sbB; (void)metaBf;
    float* inv_s  = (float*)csr;
    int*   deg_r  = (int*)(csr + (size_t)N4 * 4);
    int*   startv = (int*)(csr + (size_t)N4 * 8);
    float* cvec   = (float*)(csr + (size_t)N4 * 12);
    int*   bkt    = (int*)(csr + (size_t)N4 * 16);
    unsigned* Wb  = (unsigned*)(csr + (size_t)N4 * 16 + 8192);
    int *scur = bkt, *rcur = bkt + 512, *flag = bkt + 1024;

    hipMemsetAsync(bkt, 0, 1028 * 4, stream);

    int SG = 1, PB = 256;
    k_front<<<SG + PB, 512, 0, stream>>>(x, (unsigned*)d_ws, N * 32, 0, W, Wb, adj, flag,
                                         scur, rcur, sbuf, rbuf, E, N, NBK, SG);
    k_invs<<<NBK, 256, 0, stream>>>(sbuf, scur, inv_s, N);
    k_sort<<<NBK, 256, 0, stream>>>(rbuf, rcur, inv_s, deg_r, startv, N);
    k_aggregate_fb<<<(N + 3) / 4, 256, 0, stream>>>(x, startv, deg_r, rbuf, out0, cvec, N, RB);
    k_matmul_fb<<<(N + 63) / 64, 256, 0, stream>>>(out0, Wb, bias, cvec, deg_r, N);
    k_adjcopy<<<(2 * E + 255) / 256, 256, 0, stream>>>(adj, flag, out1, 2 * E);
}

// Round 8
// 230.986 us; speedup vs baseline: 1.6578x; 1.6578x over previous
//
#include <hip/hip_runtime.h>
#include <hip/hip_bf16.h>
#include <hip/hip_fp16.h>

typedef __attribute__((ext_vector_type(8))) short short8;   // 8 bf16 in 4 VGPRs
typedef __attribute__((ext_vector_type(4))) float floatx4;  // MFMA accumulator

#define DFEAT 128
#define BCAP 5120    // per-256-node-bucket edge cap (mean 4092, +16 sigma)
#define WSTR 136     // LDS row stride (ushorts): 16B-aligned, <=2-way bank aliasing
#define MAXNBK 400   // bucket count cap (ceil(100000/256)=391)

__device__ __forceinline__ int clampi(int v, int lo, int hi) {
    return v < lo ? lo : (v > hi ? hi : v);
}
__device__ __forceinline__ ushort f2bf(float f) {  // RNE f32->bf16 bits
    unsigned u = __float_as_uint(f);
    unsigned r = (u + 0x7FFFu + ((u >> 16) & 1u)) >> 16;
    return (ushort)r;
}
__device__ __forceinline__ float bf2f(ushort u) {
    return __uint_as_float(((unsigned)u) << 16);
}
__device__ __forceinline__ float h16tof(ushort hb) {
    __half_raw hr; hr.x = hb;
    return __half2float((__half)hr);
}
__device__ __forceinline__ unsigned f2bf8_sw(float f) {   // f32 -> e5m2 byte
    __half h = __float2half(f);
    __half_raw hr = (__half_raw)h;
    unsigned u = (unsigned)hr.x;
    return (u + 0x7Fu + ((u >> 8) & 1u)) >> 8;
}
__device__ __forceinline__ unsigned packbf8x4(float4 v) {
#if __has_builtin(__builtin_amdgcn_cvt_pk_bf8_f32)
    int lo = __builtin_amdgcn_cvt_pk_bf8_f32(v.x, v.y, 0, false);
    int full = __builtin_amdgcn_cvt_pk_bf8_f32(v.z, v.w, lo, true);
    return (unsigned)full;
#else
    return f2bf8_sw(v.x) | (f2bf8_sw(v.y) << 8) | (f2bf8_sw(v.z) << 16) | (f2bf8_sw(v.w) << 24);
#endif
}
__device__ __forceinline__ float2 bf8x2tof(int w) {       // 2 e5m2 (low 16b) -> 2 f32
#if __has_builtin(__builtin_amdgcn_cvt_pk_f32_bf8)
    typedef __attribute__((ext_vector_type(2))) float f2v;
    f2v r = __builtin_amdgcn_cvt_pk_f32_bf8(w, false);
    float2 o; o.x = r[0]; o.y = r[1];
    return o;
#else
    float2 o;
    o.x = h16tof((ushort)((w & 0xFF) << 8));
    o.y = h16tof((ushort)(w & 0xFF00));
    return o;
#endif
}

__device__ __forceinline__ int ldS(const int* adj, int f, int E, int e) {
    return f ? adj[2 * (size_t)e] : adj[e];
}
__device__ __forceinline__ int ldR(const int* adj, int f, int E, int e) {
    return f ? adj[2 * ((size_t)E + e)] : adj[(size_t)E + e];
}

// ---------------- k_front: stage blocks + part2 blocks (role-split) ----------------
// part2 uses PER-WAVE privatized LDS histograms+cursors (R5-proven): only ~200K global
// atomics total (bucket reservations) -- global per-edge atomics cost ~32B HBM traffic
// each (R6 lesson) and are avoided.
__global__ __launch_bounds__(512) void k_front(const float* __restrict__ x,
                                               unsigned* __restrict__ xs, int n32, int staged,
                                               const float* __restrict__ W, unsigned* __restrict__ Wb,
                                               const int* __restrict__ adj, int* __restrict__ flag_g,
                                               int* __restrict__ scur, int* __restrict__ rcur,
                                               unsigned char* __restrict__ sbuf, unsigned* __restrict__ rbuf,
                                               int E, int N, int NBK, int SG) {
    int t = threadIdx.x;
    int b = blockIdx.x;
    if (b < SG) {
        if (b == 0) {                                 // W f32 -> packed bf16x2
            for (int i = t; i < 8192; i += 512) {
                float2 v = ((const float2*)W)[i];
                Wb[i] = (unsigned)f2bf(v.x) | ((unsigned)f2bf(v.y) << 16);
            }
        }
        if (staged) {
            int stride = SG * 512;
            for (int i = b * 512 + t; i < n32; i += stride)
                xs[i] = packbf8x4(((const float4*)x)[i]);
        }
        return;
    }
    __shared__ int hs[8 * MAXNBK], hr[8 * MAXNBK];   // per-wave private bins (25.6KB)
    __shared__ int bs[MAXNBK], br[MAXNBK];           // per-block global bases
    __shared__ int fsh;
    int pb = b - SG;
    int PB = gridDim.x - SG;
    int wv = t >> 6, ln = t & 63;
    if (t < 64) {                                     // self-detect adj dtype
        int nz = 0;
        for (int i = t; i < 256; i += 64) nz |= adj[2 * i + 1];
        #pragma unroll
        for (int off = 32; off > 0; off >>= 1) nz |= __shfl_down(nz, off);
        if (t == 0) { fsh = (nz == 0) ? 1 : 0; if (pb == 0) flag_g[0] = fsh; }
    }
    for (int i = t; i < 8 * MAXNBK; i += 512) { hs[i] = 0; hr[i] = 0; }
    __syncthreads();
    int f = fsh;
    int chunk = (E + PB - 1) / PB;
    int e0 = pb * chunk;
    int e1 = min(E, e0 + chunk);
    int span = e1 - e0;
    int wper = (span + 7) >> 3;                       // contiguous chunk per wave
    int a0 = e0 + wv * wper;
    int a1 = min(e1, a0 + wper);
    int* mys = &hs[wv * MAXNBK];
    int* myr = &hr[wv * MAXNBK];
    for (int e = a0 + ln; e < a1; e += 64) {          // pass1: wave-private histograms
        int s = clampi(ldS(adj, f, E, e), 0, N - 1);
        int r = clampi(ldR(adj, f, E, e), 0, N - 1);
        atomicAdd(&mys[s >> 8], 1);
        atomicAdd(&myr[r >> 8], 1);
    }
    __syncthreads();
    for (int i = t; i < NBK; i += 512) {              // per-wave exclusive bases + reserve
        int aS = 0, aR = 0;
        #pragma unroll
        for (int w = 0; w < 8; ++w) {
            int vS = hs[w * MAXNBK + i]; hs[w * MAXNBK + i] = aS; aS += vS;
            int vR = hr[w * MAXNBK + i]; hr[w * MAXNBK + i] = aR; aR += vR;
        }
        bs[i] = aS ? atomicAdd(&scur[i], aS) : 0;
        br[i] = aR ? atomicAdd(&rcur[i], aR) : 0;
    }
    __syncthreads();
    for (int e = a0 + ln; e < a1; e += 64) {          // pass2: wave-private cursors
        int s = clampi(ldS(adj, f, E, e), 0, N - 1);
        int r = clampi(ldR(adj, f, E, e), 0, N - 1);
        int ps = bs[s >> 8] + atomicAdd(&mys[s >> 8], 1);
        if (ps < BCAP) sbuf[(size_t)(s >> 8) * BCAP + ps] = (unsigned char)(s & 255);
        int pr = br[r >> 8] + atomicAdd(&myr[r >> 8], 1);
        if (pr < BCAP) rbuf[(size_t)(r >> 8) * BCAP + pr] = ((unsigned)(r & 255) << 17) | (unsigned)s;
    }
}

// ---------------- per-bucket sender-degree histogram -> inv_s ----------------
__global__ __launch_bounds__(256) void k_invs(const unsigned char* __restrict__ sbuf,
                                              const int* __restrict__ scur,
                                              float* __restrict__ inv_s, int N) {
    __shared__ int h[256];
    int b = blockIdx.x, t = threadIdx.x;
    int sc = min(scur[b], BCAP);
    const unsigned char* sb = sbuf + (size_t)b * BCAP;
    h[t] = 0;
    __syncthreads();
    for (int i = t; i < sc; i += 256) atomicAdd(&h[sb[i]], 1);
    __syncthreads();
    int node = (b << 8) + t;
    if (node < N) inv_s[node] = rsqrtf(fmaxf((float)h[t], 1.0f));
}

// ---------------- per-bucket receiver counting sort; pack e5m2(inv_s[s]) in bits 24-31 ----------------
__global__ __launch_bounds__(256) void k_sort(unsigned* __restrict__ rbuf,
                                              const int* __restrict__ rcur,
                                              const float* __restrict__ inv_s,
                                              int* __restrict__ deg_r, int* __restrict__ startv,
                                              int N) {
    __shared__ __align__(16) unsigned pk[BCAP];
    __shared__ int h[256], off[256];
    int b = blockIdx.x, t = threadIdx.x;
    int node = (b << 8) + t;
    int cnt = min(rcur[b], BCAP);
    unsigned* rb = rbuf + (size_t)b * BCAP;
    int cnt4 = cnt >> 2;
    const uint4* rb4 = (const uint4*)rb;
    for (int i = t; i < cnt4; i += 256) ((uint4*)pk)[i] = rb4[i];
    for (int i = (cnt4 << 2) + t; i < cnt; i += 256) pk[i] = rb[i];
    h[t] = 0;
    __syncthreads();
    for (int i = t; i < cnt; i += 256) atomicAdd(&h[pk[i] >> 17], 1);
    __syncthreads();
    int hv = h[t];
    off[t] = hv;
    __syncthreads();
    for (int o = 1; o < 256; o <<= 1) {
        int v = (t >= o) ? off[t - o] : 0;
        __syncthreads();
        off[t] += v;
        __syncthreads();
    }
    int excl = off[t] - hv;
    if (node < N) { deg_r[node] = hv; startv[node] = b * BCAP + excl; }
    __syncthreads();
    h[t] = excl;  // cursors
    __syncthreads();
    for (int i = t; i < cnt; i += 256) {
        unsigned v = pk[i];
        int s = (int)(v & 0x1FFFFu);
        unsigned iv8 = f2bf8_sw(inv_s[clampi(s, 0, N - 1)]);
        int pos = atomicAdd(&h[v >> 17], 1);
        if (pos >= 0 && pos < cnt) rb[pos] = (v & 0x1FFFFu) | (iv8 << 24);
    }
}

// ---------------- k_back: fused aggregate(LDS) + MFMA + silu + adjcopy ----------------
// Aggregation is 4-NODE INTERLEAVED with clamp-and-mask (no control flow between the
// 16 gathers per iteration): mean degree is only 16, so per-node sequential batches
// left just 8 loads in flight; interleaving all 4 wave-nodes gives 16. cnt/base are
// wave-uniform scalars so masking costs no VALU. NT stores keep xs hot in cache.
__global__ __launch_bounds__(512) void k_back(const ushort* __restrict__ xs,
                                              const float* __restrict__ bias,
                                              const unsigned* __restrict__ Wb,
                                              const int* __restrict__ startv,
                                              const int* __restrict__ deg_r,
                                              const unsigned* __restrict__ esrc,
                                              float* __restrict__ out0, int N, int RB, int ntiles,
                                              const int* __restrict__ adj, const int* __restrict__ flag,
                                              float* __restrict__ out1, int n1) {
    __shared__ ushort Wt[128 * WSTR];   // 34816 B
    __shared__ ushort At[32 * WSTR];    // 8704 B
    __shared__ float csrow[32], invrow[32];
    int tid = threadIdx.x;

    if ((int)blockIdx.x >= ntiles) {    // adjcopy role
        int f = flag[0];
        int nb = gridDim.x - ntiles;
        for (int i = ((int)blockIdx.x - ntiles) * 512 + tid; i < n1; i += nb * 512) {
            int v = f ? adj[2 * (size_t)i] : adj[i];
            __builtin_nontemporal_store(bf2f(f2bf((float)v)), &out1[i]);
        }
        return;
    }

    int m0 = blockIdx.x * 32;
    for (int i = tid; i < 8192; i += 512) {          // stage W (pre-packed bf16)
        unsigned v = Wb[i];
        int row = i >> 6, col = (2 * i) & 127;
        *(unsigned*)(&Wt[row * WSTR + col]) = v;
    }

    int w = tid >> 6, d = tid & 63;
    int cntk[4], basek[4];
    #pragma unroll
    for (int k = 0; k < 4; ++k) {
        int node = m0 + w * 4 + k;
        int c = 0, bse = 0;
        if (node < N) {
            c = clampi(deg_r[node], 0, BCAP);
            bse = clampi(startv[node], 0, RB - (c > 0 ? c : 1));
        }
        cntk[k] = __builtin_amdgcn_readfirstlane(c);
        basek[k] = __builtin_amdgcn_readfirstlane(bse);
    }
    int cmax = max(max(cntk[0], cntk[1]), max(cntk[2], cntk[3]));
    float A0[4] = {0.f, 0.f, 0.f, 0.f};
    float A1[4] = {0.f, 0.f, 0.f, 0.f};
    float CS[4] = {0.f, 0.f, 0.f, 0.f};

    for (int j = 0; j < cmax; j += 4) {
        unsigned qv[4][4];
        #pragma unroll
        for (int k = 0; k < 4; ++k) {
            #pragma unroll
            for (int t2 = 0; t2 < 4; ++t2) {
                int idx = j + t2;
                int lim = cntk[k] - 1;
                if (lim < 0) lim = 0;
                if (idx > lim) idx = lim;            // clamp: wasted loads hit cached line
                qv[k][t2] = esrc[basek[k] + idx];    // wave-uniform address (scalar path)
            }
        }
        int rv[4][4];
        #pragma unroll
        for (int k = 0; k < 4; ++k) {
            #pragma unroll
            for (int t2 = 0; t2 < 4; ++t2)
                rv[k][t2] = (int)xs[((qv[k][t2] & 0x1FFFFu) << 6) + d];
        }
        #pragma unroll
        for (int k = 0; k < 4; ++k) {
            #pragma unroll
            for (int t2 = 0; t2 < 4; ++t2) {
                float v = ((j + t2) < cntk[k]) ? h16tof((ushort)((qv[k][t2] >> 16) & 0xFF00u)) : 0.f;
                float2 f2v_ = bf8x2tof(rv[k][t2]);
                A0[k] += v * f2v_.x;
                A1[k] += v * f2v_.y;
                CS[k] += v;
            }
        }
    }

    #pragma unroll
    for (int k = 0; k < 4; ++k) {
        int nl = w * 4 + k;
        ushort2 p; p.x = f2bf(A0[k]); p.y = f2bf(A1[k]);
        *(ushort2*)(&At[nl * WSTR + 2 * d]) = p;
        if (d == 0) {
            csrow[nl] = CS[k];
            invrow[nl] = rsqrtf(fmaxf((float)cntk[k], 1.0f));
        }
    }
    __syncthreads();

    int quad = d >> 4, r16 = d & 15;
    int rt = w & 1;
    short8 a[4];
    #pragma unroll
    for (int g = 0; g < 4; ++g)
        a[g] = *(const short8*)(&At[(rt * 16 + r16) * WSTR + g * 32 + quad * 8]);

    #pragma unroll
    for (int half = 0; half < 2; ++half) {
        int ct = (w >> 1) + half * 4;
        floatx4 acc = {0.f, 0.f, 0.f, 0.f};
        #pragma unroll
        for (int g = 0; g < 4; ++g) {
            short8 bb = *(const short8*)(&Wt[(ct * 16 + r16) * WSTR + g * 32 + quad * 8]);
            acc = __builtin_amdgcn_mfma_f32_16x16x32_bf16(a[g], bb, acc, 0, 0, 0);
        }
        int dcol = ct * 16 + r16;
        float bc = bias[dcol];
        #pragma unroll
        for (int g = 0; g < 4; ++g) {
            int ml = rt * 16 + quad * 4 + g;
            int grow = m0 + ml;
            if (grow < N) {
                float v = (acc[g] + csrow[ml] * bc) * invrow[ml];
                float z = v / (1.0f + __expf(-v));            // silu
                if (!(z > -50.0f && z < 50.0f)) z = 0.0f;     // insurance, no-op when correct
                __builtin_nontemporal_store(z, &out0[(size_t)grow * DFEAT + dcol]);
            }
        }
    }
}

// ================= unstaged fallback (not hit when ws is big enough) =================
__global__ __launch_bounds__(256) void k_aggregate_fb(const float* __restrict__ x,
                                                      const int* __restrict__ startv,
                                                      const int* __restrict__ deg_r,
                                                      const unsigned* __restrict__ esrc,
                                                      float* __restrict__ xa,
                                                      float* __restrict__ cvec, int N, int RB) {
    int node = blockIdx.x * 4 + (threadIdx.x >> 6);
    int d = threadIdx.x & 63;
    if (node >= N) return;
    int cnt = clampi(deg_r[node], 0, BCAP);
    int base = clampi(startv[node], 0, RB - cnt);
    cnt = __builtin_amdgcn_readfirstlane(cnt);
    base = __builtin_amdgcn_readfirstlane(base);
    const unsigned* ep = esrc + base;
    float a0 = 0.f, a1 = 0.f, cs = 0.f;
    for (int j = 0; j < cnt; ++j) {
        unsigned w0 = ep[j];
        int s0 = (int)(w0 & 0x1FFFFu);
        float v0 = h16tof((ushort)((w0 >> 16) & 0xFF00u));
        float2 f0 = ((const float2*)x)[(size_t)s0 * 64 + d];
        a0 += v0 * f0.x; a1 += v0 * f0.y;
        cs += v0;
    }
    float2 o; o.x = a0; o.y = a1;
    ((float2*)xa)[(size_t)node * 64 + d] = o;
    if (d == 0) cvec[node] = cs;
}

__global__ __launch_bounds__(256) void k_matmul_fb(float* __restrict__ xa,
                                                   const unsigned* __restrict__ Wb,
                                                   const float* __restrict__ bias,
                                                   const float* __restrict__ c,
                                                   const int* __restrict__ deg_r, int M) {
    __shared__ ushort Wt[128 * WSTR];
    __shared__ ushort At[64 * WSTR];
    int tid = threadIdx.x;
    int m0 = blockIdx.x * 64;
    for (int i = tid; i < 8192; i += 256) {
        unsigned v = Wb[i];
        int row = i >> 6, col = (2 * i) & 127;
        *(unsigned*)(&Wt[row * WSTR + col]) = v;
    }
    for (int i = tid; i < 4096; i += 256) {
        int row = i >> 6, col = (2 * i) & 127;
        int grow = m0 + row;
        float2 v;
        if (grow < M) v = ((const float2*)xa)[(size_t)grow * 64 + (col >> 1)];
        else { v.x = 0.f; v.y = 0.f; }
        ushort2 p; p.x = f2bf(v.x); p.y = f2bf(v.y);
        *(ushort2*)(&At[row * WSTR + col]) = p;
    }
    __syncthreads();
    int wid = tid >> 6, lane = tid & 63;
    int quad = lane >> 4, r16 = lane & 15;
    short8 a[4];
    #pragma unroll
    for (int g = 0; g < 4; ++g)
        a[g] = *(const short8*)(&At[(wid * 16 + r16) * WSTR + g * 32 + quad * 8]);
    int rbl = wid * 16 + quad * 4;
    float cg[4], invr[4];
    #pragma unroll
    for (int g = 0; g < 4; ++g) {
        int row = min(m0 + rbl + g, M - 1);
        cg[g] = c[row];
        invr[g] = rsqrtf(fmaxf((float)deg_r[row], 1.0f));
    }
    #pragma unroll
    for (int nt = 0; nt < 8; ++nt) {
        floatx4 acc = {0.f, 0.f, 0.f, 0.f};
        #pragma unroll
        for (int g = 0; g < 4; ++g) {
            short8 bb = *(const short8*)(&Wt[(nt * 16 + r16) * WSTR + g * 32 + quad * 8]);
            acc = __builtin_amdgcn_mfma_f32_16x16x32_bf16(a[g], bb, acc, 0, 0, 0);
        }
        int dcol = nt * 16 + r16;
        float bc = bias[dcol];
        #pragma unroll
        for (int g = 0; g < 4; ++g) {
            int grow = m0 + rbl + g;
            if (grow < M) {
                float v = (acc[g] + cg[g] * bc) * invr[g];
                float z = v / (1.0f + __expf(-v));
                if (!(z > -50.0f && z < 50.0f)) z = 0.0f;
                xa[(size_t)grow * DFEAT + dcol] = z;
            }
        }
    }
}

__global__ void k_adjcopy(const int* __restrict__ adj, const int* __restrict__ flag,
                          float* __restrict__ out, int n) {
    int i = blockIdx.x * 256 + threadIdx.x;
    if (i >= n) return;
    int f = flag[0];
    int v = f ? adj[2 * (size_t)i] : adj[i];
    out[i] = bf2f(f2bf((float)v));
}

extern "C" void kernel_launch(void* const* d_in, const int* in_sizes, int n_in,
                              void* d_out, int out_size, void* d_ws, size_t ws_size,
                              hipStream_t stream) {
    const float* x    = (const float*)d_in[0];   // f32 [N,128]
    const int*   adj  = (const int*)d_in[1];     // int32 or int64 [2,E]
    const float* W    = (const float*)d_in[2];   // f32 [128,128]
    const float* bias = (const float*)d_in[3];   // f32 [128]

    const int N = in_sizes[0] / DFEAT;           // 100000
    const int E = (out_size - N * DFEAT) / 2;    // 1600000
    const int NBK = (N + 255) >> 8;              // 391 buckets of 256 nodes
    const int N4 = ((N + 255) / 256) * 256;
    const int RB = NBK * BCAP;

    float* out  = (float*)d_out;
    float* out0 = out;
    float* out1 = out + (size_t)N * DFEAT;

    size_t xsB  = (size_t)N * DFEAT;             // 12.8 MB e5m2 rows
    size_t sbB  = ((size_t)NBK * BCAP + 255) & ~(size_t)255;
    size_t rbB  = (size_t)RB * 4;
    size_t metaB = (size_t)N4 * 16 + 8192;
    size_t need = xsB + sbB + rbB + metaB + 32768;
    int staged = (ws_size >= need) ? 1 : 0;

    unsigned char* sbuf;
    unsigned* rbuf;
    char* csr;
    ushort* xs = (ushort*)d_ws;
    if (staged) {
        sbuf = (unsigned char*)d_ws + xsB;
        rbuf = (unsigned*)((char*)d_ws + xsB + sbB);
        csr  = (char*)d_ws + xsB + sbB + rbB;
    } else {
        sbuf = (unsigned char*)d_out;            // out0 head (dead until aggregate)
        rbuf = (unsigned*)out1;                  // out1 head
        csr  = (char*)out1 + rbB;                // out1 tail
    }
    float* inv_s  = (float*)csr;
    int*   deg_r  = (int*)(csr + (size_t)N4 * 4);
    int*   startv = (int*)(csr + (size_t)N4 * 8);
    float* cvec   = (float*)(csr + (size_t)N4 * 12);
    int*   bkt    = (int*)(csr + (size_t)N4 * 16);
    unsigned* Wb  = (unsigned*)(csr + metaB);
    int *scur = bkt, *rcur = bkt + 512, *flag = bkt + 1024;

    hipMemsetAsync(bkt, 0, 1028 * 4, stream);    // scur, rcur, flag

    int SG = staged ? 512 : 1;
    int PB = 256;
    k_front<<<SG + PB, 512, 0, stream>>>(x, (unsigned*)xs, N * 32, staged, W, Wb, adj, flag,
                                         scur, rcur, sbuf, rbuf, E, N, NBK, SG);
    k_invs<<<NBK, 256, 0, stream>>>(sbuf, scur, inv_s, N);
    k_sort<<<NBK, 256, 0, stream>>>(rbuf, rcur, inv_s, deg_r, startv, N);

    if (staged) {
        int ntiles = (N + 31) / 32;
        k_back<<<ntiles + 256, 512, 0, stream>>>(xs, bias, Wb, startv, deg_r, rbuf,
                                                 out0, N, RB, ntiles, adj, flag, out1, 2 * E);
    } else {
        k_aggregate_fb<<<(N + 3) / 4, 256, 0, stream>>>(x, startv, deg_r, rbuf, out0, cvec, N, RB);
        k_matmul_fb<<<(N + 63) / 64, 256, 0, stream>>>(out0, Wb, bias, cvec, deg_r, N);
        k_adjcopy<<<(2 * E + 255) / 256, 256, 0, stream>>>(adj, flag, out1, 2 * E);
    }
}